// Round 1
// baseline (2490.190 us; speedup 1.0000x reference)
//
#include <hip/hip_runtime.h>
#include <hip/hip_fp16.h>

#define H_ 1024
#define B_ 256
#define T_ 256
#define C_ 10

typedef _Float16 f16x8 __attribute__((ext_vector_type(8)));
typedef float f32x4 __attribute__((ext_vector_type(4)));

__device__ __forceinline__ float sigm_f(float v) { return 1.f / (1.f + __expf(-v)); }
__device__ __forceinline__ float tanh_f(float v) {
  v = fminf(fmaxf(v, -15.f), 15.f);
  float e = __expf(2.f * v);
  return (e - 1.f) / (e + 1.f);
}

// Persistent LSTM kernel.
// Grid: 256 WGs = 32 row-groups (r) x 8 col-groups (g). blockIdx&7 = g so each
// col-group tends to land on one XCD (perf only; correctness is agent-scope).
// Each WG: 32 hidden units x 32 batch cols, all 4 gates. 8 waves = 2 M-groups x
// 4 K-slices; weights (M=64 x K=256 fp16 per wave) live in 128 VGPRs.
// Weight row permutation: m = 4*u_local + gate (gate: 0=g,1=i,2=f,3=o) so a
// lane's float4 accumulator holds the 4 gates of one (unit, col).
__global__ __launch_bounds__(512, 2) void lstm_main(
    const float* __restrict__ x,
    const float* __restrict__ Wgh, const float* __restrict__ Wih,
    const float* __restrict__ Wfh, const float* __restrict__ Woh,
    const float* __restrict__ Wgx, const float* __restrict__ Wix,
    const float* __restrict__ Wfx, const float* __restrict__ Wox,
    const float* __restrict__ bg, const float* __restrict__ bi,
    const float* __restrict__ bf, const float* __restrict__ bo,
    _Float16* __restrict__ hT, unsigned int* __restrict__ cnt)
{
  const int bid  = blockIdx.x;
  const int g    = bid & 7;      // col group (-> XCD heuristic)
  const int r    = bid >> 3;     // row group 0..31
  const int tid  = threadIdx.x;
  const int wid  = tid >> 6;     // wave 0..7
  const int lane = tid & 63;
  const int mg   = wid >> 2;     // M-group 0..1
  const int kg   = wid & 3;      // K-slice 0..3
  const int q    = lane >> 4;    // 0..3
  const int rlo  = lane & 15;
  const int c0   = g * 32;       // batch col base

  __shared__ float part[32 * 4 * 128];  // [c_local][kg][m] f32, XOR-swizzled

  // ---- A fragments: stationary weights in registers -----------------------
  // A-frag layout for mfma_f32_16x16x32_f16: lane holds A[row=lane&15][k=(lane>>4)*8+j]
  f16x8 A[32];
  {
    const int gate = rlo & 3;  // since m = mg*64 + mt*16 + rlo, gate = m&3 = rlo&3
    const float* Wsel = (gate == 0) ? Wgh : (gate == 1) ? Wih : (gate == 2) ? Wfh : Woh;
    #pragma unroll
    for (int f = 0; f < 32; ++f) {
      const int mt  = f >> 3, kkl = f & 7;
      const int u   = mg * 16 + mt * 4 + (rlo >> 2);   // unit within WG's 32
      const int k   = kg * 256 + kkl * 32 + q * 8;
      const float4* p = reinterpret_cast<const float4*>(
          Wsel + (size_t)(r * 32 + u) * H_ + k);
      float4 lo = p[0], hi = p[1];
      f16x8 a;
      a[0]=(_Float16)lo.x; a[1]=(_Float16)lo.y; a[2]=(_Float16)lo.z; a[3]=(_Float16)lo.w;
      a[4]=(_Float16)hi.x; a[5]=(_Float16)hi.y; a[6]=(_Float16)hi.z; a[7]=(_Float16)hi.w;
      A[f] = a;
    }
  }

  // ---- per-thread elementwise constants -----------------------------------
  const int c_l = tid >> 4;   // 0..31 batch col within group
  const int uu  = tid & 15;   // unit low bits; pairs: u_local = uu, uu+16
  float wx0[4], wx1[4], bb0[4], bb1[4];
  {
    const int u0 = r * 32 + uu, u1 = u0 + 16;
    wx0[0]=Wgx[u0]; wx0[1]=Wix[u0]; wx0[2]=Wfx[u0]; wx0[3]=Wox[u0];
    wx1[0]=Wgx[u1]; wx1[1]=Wix[u1]; wx1[2]=Wfx[u1]; wx1[3]=Wox[u1];
    bb0[0]=bg[u0];  bb0[1]=bi[u0];  bb0[2]=bf[u0];  bb0[3]=bo[u0];
    bb1[0]=bg[u1];  bb1[1]=bi[u1];  bb1[2]=bf[u1];  bb1[3]=bo[u1];
  }
  float cs0 = 0.f, cs1 = 0.f;
  const float* xrow = x + (size_t)(c0 + c_l) * T_;
  unsigned int* cptr = cnt + g * 32;  // 128B-spaced counters per col-group

  for (int t = 0; t < T_; ++t) {
    // ---- wait for h(t) from all 32 WGs of this col-group ----
    if (t > 0) {
      if (tid == 0) {
        const unsigned tgt = 32u * (unsigned)t;
        int guard = 0;
        while (__hip_atomic_fetch_add(cptr, 0u, __ATOMIC_RELAXED,
                                      __HIP_MEMORY_SCOPE_AGENT) < tgt) {
          if (++guard > (1 << 22)) break;  // deadlock bailout (fails absmax, no hang)
          __builtin_amdgcn_s_sleep(2);
        }
        // one acquire: invalidates L1 + stale L2 lines for whole CU
        (void)__hip_atomic_fetch_add(cptr, 0u, __ATOMIC_ACQUIRE,
                                     __HIP_MEMORY_SCOPE_AGENT);
      }
      __syncthreads();
    }

    // ---- GEMM: preactivations for this WG's 128(M) x 32(N) tile ----
    const _Float16* hbuf = hT + (size_t)(t & 1) * (B_ * H_);
    // B-frag: lane holds B[k=(lane>>4)*8+j][col=lane&15]; hT is [B][H] so
    // hT[c][k] = h[k][c] rows are the fragments, fully contiguous 16B loads.
    const _Float16* hb0 = hbuf + (size_t)(c0 + rlo) * H_ + kg * 256 + q * 8;
    const _Float16* hb1 = hb0 + 16 * (size_t)H_;

    f32x4 acc[4][2];
    #pragma unroll
    for (int mt = 0; mt < 4; ++mt) {
      acc[mt][0] = (f32x4){0.f, 0.f, 0.f, 0.f};
      acc[mt][1] = (f32x4){0.f, 0.f, 0.f, 0.f};
    }

    #pragma unroll
    for (int kkl = 0; kkl < 8; ++kkl) {
      f16x8 b0 = *reinterpret_cast<const f16x8*>(hb0 + kkl * 32);
      f16x8 b1 = *reinterpret_cast<const f16x8*>(hb1 + kkl * 32);
      #pragma unroll
      for (int mt = 0; mt < 4; ++mt) {
        acc[mt][0] = __builtin_amdgcn_mfma_f32_16x16x32_f16(A[mt*8+kkl], b0, acc[mt][0], 0, 0, 0);
        acc[mt][1] = __builtin_amdgcn_mfma_f32_16x16x32_f16(A[mt*8+kkl], b1, acc[mt][1], 0, 0, 0);
      }
    }

    // ---- K-partials to LDS (C/D layout: col=lane&15, row=(lane>>4)*4+reg) ----
    #pragma unroll
    for (int mt = 0; mt < 4; ++mt) {
      #pragma unroll
      for (int nt = 0; nt < 2; ++nt) {
        const int c_loc = nt * 16 + rlo;
        const int m = mg * 64 + mt * 16 + 4 * q;
        unsigned addr = (unsigned)(c_loc * 2048 + kg * 512 + m * 4);
        addr ^= (unsigned)((c_loc & 7) << 4);
        *reinterpret_cast<f32x4*>(reinterpret_cast<char*>(part) + addr) = acc[mt][nt];
      }
    }
    __syncthreads();

    // ---- reduce over kg + gate nonlinearities + state update ----
    const float xv = xrow[t];
    unsigned short hbits0, hbits1;
    {
      // pair 0: u_local = uu
      unsigned lin = (unsigned)(c_l * 2048 + uu * 16);
      f32x4 s = *reinterpret_cast<const f32x4*>(
          reinterpret_cast<const char*>(part) + (lin ^ ((unsigned)(c_l & 7) << 4)));
      #pragma unroll
      for (int kgi = 1; kgi < 4; ++kgi) {
        unsigned l2 = lin + (unsigned)(kgi * 512);
        s += *reinterpret_cast<const f32x4*>(
            reinterpret_cast<const char*>(part) + (l2 ^ ((unsigned)(c_l & 7) << 4)));
      }
      float pg = s[0] + wx0[0]*xv + bb0[0];
      float pi = s[1] + wx0[1]*xv + bb0[1];
      float pf = s[2] + wx0[2]*xv + bb0[2];
      float po = s[3] + wx0[3]*xv + bb0[3];
      float gg = tanh_f(pg), ii = sigm_f(pi), ff = sigm_f(pf), oo = sigm_f(po);
      cs0 = gg * ii + cs0 * ff;
      hbits0 = __builtin_bit_cast(unsigned short, (_Float16)(tanh_f(cs0) * oo));
    }
    {
      // pair 1: u_local = uu + 16
      unsigned lin = (unsigned)(c_l * 2048 + (uu + 16) * 16);
      f32x4 s = *reinterpret_cast<const f32x4*>(
          reinterpret_cast<const char*>(part) + (lin ^ ((unsigned)(c_l & 7) << 4)));
      #pragma unroll
      for (int kgi = 1; kgi < 4; ++kgi) {
        unsigned l2 = lin + (unsigned)(kgi * 512);
        s += *reinterpret_cast<const f32x4*>(
            reinterpret_cast<const char*>(part) + (l2 ^ ((unsigned)(c_l & 7) << 4)));
      }
      float pg = s[0] + wx1[0]*xv + bb1[0];
      float pi = s[1] + wx1[1]*xv + bb1[1];
      float pf = s[2] + wx1[2]*xv + bb1[2];
      float po = s[3] + wx1[3]*xv + bb1[3];
      float gg = tanh_f(pg), ii = sigm_f(pi), ff = sigm_f(pf), oo = sigm_f(po);
      cs1 = gg * ii + cs1 * ff;
      hbits1 = __builtin_bit_cast(unsigned short, (_Float16)(tanh_f(cs1) * oo));
    }

    // ---- store h(t+1) to the other parity buffer (agent-coherent) ----
    {
      _Float16* hout = hT + (size_t)((t + 1) & 1) * (B_ * H_)
                          + (size_t)(c0 + c_l) * H_ + r * 32;
      int nb0 = __shfl_down((int)hbits0, 1);
      int nb1 = __shfl_down((int)hbits1, 1);
      if ((uu & 1) == 0) {
        unsigned v0 = (unsigned)hbits0 | ((unsigned)(unsigned short)nb0 << 16);
        unsigned v1 = (unsigned)hbits1 | ((unsigned)(unsigned short)nb1 << 16);
        __hip_atomic_store(reinterpret_cast<unsigned int*>(hout + uu), v0,
                           __ATOMIC_RELAXED, __HIP_MEMORY_SCOPE_AGENT);
        __hip_atomic_store(reinterpret_cast<unsigned int*>(hout + uu + 16), v1,
                           __ATOMIC_RELAXED, __HIP_MEMORY_SCOPE_AGENT);
      }
    }
    __syncthreads();  // drains vmcnt: all h-stores L3-acked before arrival
    if (tid == 0)
      (void)__hip_atomic_fetch_add(cptr, 1u, __ATOMIC_RELEASE,
                                   __HIP_MEMORY_SCOPE_AGENT);
  }
}

// out[b][cls] = sum_u W_ph[cls][u] * h_final[u][b] + b_p[cls]
__global__ void lstm_proj(const _Float16* __restrict__ hT,
                          const float* __restrict__ Wph,
                          const float* __restrict__ bp,
                          float* __restrict__ out)
{
  const int b = blockIdx.x;
  const int l = threadIdx.x;
  const _Float16* hrow = hT + (size_t)b * H_;  // final h is in parity-0 buffer (T even)
  float p[C_];
  #pragma unroll
  for (int cls = 0; cls < C_; ++cls) p[cls] = 0.f;
  for (int u = l; u < H_; u += 64) {
    float hv = (float)hrow[u];
    #pragma unroll
    for (int cls = 0; cls < C_; ++cls) p[cls] += hv * Wph[cls * H_ + u];
  }
  #pragma unroll
  for (int cls = 0; cls < C_; ++cls) {
    float v = p[cls];
    #pragma unroll
    for (int off = 32; off > 0; off >>= 1) v += __shfl_down(v, off);
    if (l == 0) out[b * C_ + cls] = v + bp[cls];
  }
}

extern "C" void kernel_launch(void* const* d_in, const int* in_sizes, int n_in,
                              void* d_out, int out_size, void* d_ws, size_t ws_size,
                              hipStream_t stream) {
  const float* x   = (const float*)d_in[0];
  const float* Wgx = (const float*)d_in[1];
  const float* Wgh = (const float*)d_in[2];
  const float* Wix = (const float*)d_in[3];
  const float* Wih = (const float*)d_in[4];
  const float* Wfx = (const float*)d_in[5];
  const float* Wfh = (const float*)d_in[6];
  const float* Wox = (const float*)d_in[7];
  const float* Woh = (const float*)d_in[8];
  const float* Wph = (const float*)d_in[9];
  const float* bg  = (const float*)d_in[10];
  const float* bi  = (const float*)d_in[11];
  const float* bf  = (const float*)d_in[12];
  const float* bo  = (const float*)d_in[13];
  const float* bp  = (const float*)d_in[14];
  float* out = (float*)d_out;

  // ws layout: [0,1MB) hT fp16 double buffer [2][B][H]; [1MB,+4KB) counters
  _Float16* hT = (_Float16*)d_ws;
  const size_t hT_bytes = (size_t)2 * B_ * H_ * sizeof(_Float16);  // 1 MiB
  unsigned int* cnt = (unsigned int*)((char*)d_ws + hT_bytes);

  hipMemsetAsync(d_ws, 0, hT_bytes + 4096, stream);  // h(0)=0, counters=0

  lstm_main<<<256, 512, 0, stream>>>(x, Wgh, Wih, Wfh, Woh,
                                     Wgx, Wix, Wfx, Wox,
                                     bg, bi, bf, bo, hT, cnt);
  lstm_proj<<<256, 64, 0, stream>>>(hT, Wph, bp, out);
}

// Round 2
// 2315.849 us; speedup vs baseline: 1.0753x; 1.0753x over previous
//
#include <hip/hip_runtime.h>
#include <hip/hip_fp16.h>

#define H_ 1024
#define B_ 256
#define T_ 256
#define C_ 10

typedef _Float16 f16x8 __attribute__((ext_vector_type(8)));
typedef float f32x4 __attribute__((ext_vector_type(4)));

__device__ __forceinline__ float sigm_f(float v) { return 1.f / (1.f + __expf(-v)); }
__device__ __forceinline__ float tanh_f(float v) {
  v = fminf(fmaxf(v, -15.f), 15.f);
  float e = __expf(2.f * v);
  return (e - 1.f) / (e + 1.f);
}

// Agent-scope (coherence-point) 16B load as two 8B relaxed atomic loads.
// Reads L3/IC directly -> no L1/L2 invalidation needed anywhere.
__device__ __forceinline__ f16x8 load_h8(const _Float16* p) {
  const unsigned long long* q = reinterpret_cast<const unsigned long long*>(p);
  unsigned long long lo = __hip_atomic_load(q,     __ATOMIC_RELAXED, __HIP_MEMORY_SCOPE_AGENT);
  unsigned long long hi = __hip_atomic_load(q + 1, __ATOMIC_RELAXED, __HIP_MEMORY_SCOPE_AGENT);
  union { unsigned long long u[2]; f16x8 v; } r;
  r.u[0] = lo; r.u[1] = hi;
  return r.v;
}

// Persistent LSTM kernel.
// Grid: 256 WGs = 32 row-groups (r) x 8 col-groups (g). Each WG: 32 hidden
// units x 32 batch cols, all 4 gates. 8 waves = 2 M-groups x 4 K-slices;
// weights (M=64 x K=256 fp16 per wave) stay in 128 VGPRs for all 256 steps.
// Weight row permutation m = 4*u_local + gate so a lane's float4 accumulator
// holds the 4 gate preactivations of one (unit, col).
// Sync: per-producer flags. flag[g][r] = steps completed by WG (r,g).
// Wave kg consumes h rows [256*kg, 256*kg+256) = producers r' in [8kg, 8kg+8),
// so it polls exactly 8 flags (plain atomic loads, no RMW, no cache inv).
__global__ __launch_bounds__(512, 2) void lstm_main(
    const float* __restrict__ x,
    const float* __restrict__ Wgh, const float* __restrict__ Wih,
    const float* __restrict__ Wfh, const float* __restrict__ Woh,
    const float* __restrict__ Wgx, const float* __restrict__ Wix,
    const float* __restrict__ Wfx, const float* __restrict__ Wox,
    const float* __restrict__ bg, const float* __restrict__ bi,
    const float* __restrict__ bf, const float* __restrict__ bo,
    _Float16* __restrict__ hT, unsigned int* __restrict__ flags)
{
  const int bid  = blockIdx.x;
  const int g    = bid & 7;      // col group
  const int r    = bid >> 3;     // row group 0..31
  const int tid  = threadIdx.x;
  const int wid  = tid >> 6;     // wave 0..7
  const int lane = tid & 63;
  const int mg   = wid >> 2;     // M-group 0..1
  const int kg   = wid & 3;      // K-slice 0..3
  const int q    = lane >> 4;    // 0..3
  const int rlo  = lane & 15;
  const int c0   = g * 32;       // batch col base

  __shared__ float part[32 * 4 * 128];  // [c_local][kg][m] f32, XOR-swizzled

  // ---- A fragments: stationary weights in registers -----------------------
  f16x8 A[32];
  {
    const int gate = rlo & 3;
    const float* Wsel = (gate == 0) ? Wgh : (gate == 1) ? Wih : (gate == 2) ? Wfh : Woh;
    #pragma unroll
    for (int f = 0; f < 32; ++f) {
      const int mt  = f >> 3, kkl = f & 7;
      const int u   = mg * 16 + mt * 4 + (rlo >> 2);
      const int k   = kg * 256 + kkl * 32 + q * 8;
      const float4* p = reinterpret_cast<const float4*>(
          Wsel + (size_t)(r * 32 + u) * H_ + k);
      float4 lo = p[0], hi = p[1];
      f16x8 a;
      a[0]=(_Float16)lo.x; a[1]=(_Float16)lo.y; a[2]=(_Float16)lo.z; a[3]=(_Float16)lo.w;
      a[4]=(_Float16)hi.x; a[5]=(_Float16)hi.y; a[6]=(_Float16)hi.z; a[7]=(_Float16)hi.w;
      A[f] = a;
    }
  }

  // ---- per-thread elementwise constants -----------------------------------
  const int c_l = tid >> 4;
  const int uu  = tid & 15;
  float wx0[4], wx1[4], bb0[4], bb1[4];
  {
    const int u0 = r * 32 + uu, u1 = u0 + 16;
    wx0[0]=Wgx[u0]; wx0[1]=Wix[u0]; wx0[2]=Wfx[u0]; wx0[3]=Wox[u0];
    wx1[0]=Wgx[u1]; wx1[1]=Wix[u1]; wx1[2]=Wfx[u1]; wx1[3]=Wox[u1];
    bb0[0]=bg[u0];  bb0[1]=bi[u0];  bb0[2]=bf[u0];  bb0[3]=bo[u0];
    bb1[0]=bg[u1];  bb1[1]=bi[u1];  bb1[2]=bf[u1];  bb1[3]=bo[u1];
  }
  float cs0 = 0.f, cs1 = 0.f;
  const float* xrow = x + (size_t)(c0 + c_l) * T_;

  // my wave's 8 producer flags (64B-spaced): flag(g, 8*kg + j)
  unsigned int* myflags = flags + ((size_t)(g * 32 + kg * 8 + (lane & 7)) * 16);
  // my WG's own flag
  unsigned int* ownflag = flags + ((size_t)(g * 32 + r) * 16);

  for (int t = 0; t < T_; ++t) {
    const float xv = xrow[t];  // L1-resident (no cache inv in this design)

    // ---- per-wave wait: only the 8 producers feeding this K-slice ----
    if (t > 0) {
      const unsigned tgt = (unsigned)t;
      int guard = 0;
      for (;;) {
        unsigned v = tgt;
        if (lane < 8)
          v = __hip_atomic_load(myflags, __ATOMIC_RELAXED, __HIP_MEMORY_SCOPE_AGENT);
        if (__all((int)(v >= tgt))) break;
        if (++guard > (1 << 20)) break;  // bailout: fails absmax, never hangs
        __builtin_amdgcn_s_sleep(1);
      }
      // compiler/ordering fence only -- no L1/L2 invalidate (h reads are
      // agent-scope loads that read the coherence point directly)
      __builtin_amdgcn_fence(__ATOMIC_ACQUIRE, "workgroup");
      asm volatile("" ::: "memory");
    }

    // ---- GEMM: preactivations for this WG's 128(M) x 32(N) tile ----
    const _Float16* hbuf = hT + (size_t)(t & 1) * (B_ * H_);
    const _Float16* hb0 = hbuf + (size_t)(c0 + rlo) * H_ + kg * 256 + q * 8;
    const _Float16* hb1 = hb0 + 16 * (size_t)H_;

    f32x4 acc[4][2];
    #pragma unroll
    for (int mt = 0; mt < 4; ++mt) {
      acc[mt][0] = (f32x4){0.f, 0.f, 0.f, 0.f};
      acc[mt][1] = (f32x4){0.f, 0.f, 0.f, 0.f};
    }

    #pragma unroll
    for (int kkl = 0; kkl < 8; ++kkl) {
      f16x8 b0 = load_h8(hb0 + kkl * 32);
      f16x8 b1 = load_h8(hb1 + kkl * 32);
      #pragma unroll
      for (int mt = 0; mt < 4; ++mt) {
        acc[mt][0] = __builtin_amdgcn_mfma_f32_16x16x32_f16(A[mt*8+kkl], b0, acc[mt][0], 0, 0, 0);
        acc[mt][1] = __builtin_amdgcn_mfma_f32_16x16x32_f16(A[mt*8+kkl], b1, acc[mt][1], 0, 0, 0);
      }
    }

    // ---- K-partials to LDS (C/D layout: col=lane&15, row=(lane>>4)*4+reg) ----
    #pragma unroll
    for (int mt = 0; mt < 4; ++mt) {
      #pragma unroll
      for (int nt = 0; nt < 2; ++nt) {
        const int c_loc = nt * 16 + rlo;
        const int m = mg * 64 + mt * 16 + 4 * q;
        unsigned addr = (unsigned)(c_loc * 2048 + kg * 512 + m * 4);
        addr ^= (unsigned)((c_loc & 7) << 4);
        *reinterpret_cast<f32x4*>(reinterpret_cast<char*>(part) + addr) = acc[mt][nt];
      }
    }
    __syncthreads();

    // ---- reduce over kg + gate nonlinearities + state update ----
    unsigned short hbits0, hbits1;
    {
      unsigned lin = (unsigned)(c_l * 2048 + uu * 16);
      f32x4 s = *reinterpret_cast<const f32x4*>(
          reinterpret_cast<const char*>(part) + (lin ^ ((unsigned)(c_l & 7) << 4)));
      #pragma unroll
      for (int kgi = 1; kgi < 4; ++kgi) {
        unsigned l2 = lin + (unsigned)(kgi * 512);
        s += *reinterpret_cast<const f32x4*>(
            reinterpret_cast<const char*>(part) + (l2 ^ ((unsigned)(c_l & 7) << 4)));
      }
      float pg = s[0] + wx0[0]*xv + bb0[0];
      float pi = s[1] + wx0[1]*xv + bb0[1];
      float pf = s[2] + wx0[2]*xv + bb0[2];
      float po = s[3] + wx0[3]*xv + bb0[3];
      float gg = tanh_f(pg), ii = sigm_f(pi), ff = sigm_f(pf), oo = sigm_f(po);
      cs0 = gg * ii + cs0 * ff;
      hbits0 = __builtin_bit_cast(unsigned short, (_Float16)(tanh_f(cs0) * oo));
    }
    {
      unsigned lin = (unsigned)(c_l * 2048 + (uu + 16) * 16);
      f32x4 s = *reinterpret_cast<const f32x4*>(
          reinterpret_cast<const char*>(part) + (lin ^ ((unsigned)(c_l & 7) << 4)));
      #pragma unroll
      for (int kgi = 1; kgi < 4; ++kgi) {
        unsigned l2 = lin + (unsigned)(kgi * 512);
        s += *reinterpret_cast<const f32x4*>(
            reinterpret_cast<const char*>(part) + (l2 ^ ((unsigned)(c_l & 7) << 4)));
      }
      float pg = s[0] + wx1[0]*xv + bb1[0];
      float pi = s[1] + wx1[1]*xv + bb1[1];
      float pf = s[2] + wx1[2]*xv + bb1[2];
      float po = s[3] + wx1[3]*xv + bb1[3];
      float gg = tanh_f(pg), ii = sigm_f(pi), ff = sigm_f(pf), oo = sigm_f(po);
      cs1 = gg * ii + cs1 * ff;
      hbits1 = __builtin_bit_cast(unsigned short, (_Float16)(tanh_f(cs1) * oo));
    }

    // ---- store h(t+1) to the other parity buffer (agent-coherent) ----
    {
      _Float16* hout = hT + (size_t)((t + 1) & 1) * (B_ * H_)
                          + (size_t)(c0 + c_l) * H_ + r * 32;
      int nb0 = __shfl_down((int)hbits0, 1);
      int nb1 = __shfl_down((int)hbits1, 1);
      if ((uu & 1) == 0) {
        unsigned v0 = (unsigned)hbits0 | ((unsigned)(unsigned short)nb0 << 16);
        unsigned v1 = (unsigned)hbits1 | ((unsigned)(unsigned short)nb1 << 16);
        __hip_atomic_store(reinterpret_cast<unsigned int*>(hout + uu), v0,
                           __ATOMIC_RELAXED, __HIP_MEMORY_SCOPE_AGENT);
        __hip_atomic_store(reinterpret_cast<unsigned int*>(hout + uu + 16), v1,
                           __ATOMIC_RELAXED, __HIP_MEMORY_SCOPE_AGENT);
      }
    }
    // barrier drains vmcnt for ALL threads -> every h store is acked at the
    // coherence point before any thread can publish the flag below
    __syncthreads();
    if (tid == 0)
      __hip_atomic_store(ownflag, (unsigned)(t + 1),
                         __ATOMIC_RELAXED, __HIP_MEMORY_SCOPE_AGENT);
  }
}

// out[b][cls] = sum_u W_ph[cls][u] * h_final[u][b] + b_p[cls]
__global__ void lstm_proj(const _Float16* __restrict__ hT,
                          const float* __restrict__ Wph,
                          const float* __restrict__ bp,
                          float* __restrict__ out)
{
  const int b = blockIdx.x;
  const int l = threadIdx.x;
  const _Float16* hrow = hT + (size_t)b * H_;  // T even -> final h in parity-0
  float p[C_];
  #pragma unroll
  for (int cls = 0; cls < C_; ++cls) p[cls] = 0.f;
  for (int u = l; u < H_; u += 64) {
    float hv = (float)hrow[u];
    #pragma unroll
    for (int cls = 0; cls < C_; ++cls) p[cls] += hv * Wph[cls * H_ + u];
  }
  #pragma unroll
  for (int cls = 0; cls < C_; ++cls) {
    float v = p[cls];
    #pragma unroll
    for (int off = 32; off > 0; off >>= 1) v += __shfl_down(v, off);
    if (l == 0) out[b * C_ + cls] = v + bp[cls];
  }
}

extern "C" void kernel_launch(void* const* d_in, const int* in_sizes, int n_in,
                              void* d_out, int out_size, void* d_ws, size_t ws_size,
                              hipStream_t stream) {
  const float* x   = (const float*)d_in[0];
  const float* Wgx = (const float*)d_in[1];
  const float* Wgh = (const float*)d_in[2];
  const float* Wix = (const float*)d_in[3];
  const float* Wih = (const float*)d_in[4];
  const float* Wfx = (const float*)d_in[5];
  const float* Wfh = (const float*)d_in[6];
  const float* Wox = (const float*)d_in[7];
  const float* Woh = (const float*)d_in[8];
  const float* Wph = (const float*)d_in[9];
  const float* bg  = (const float*)d_in[10];
  const float* bi  = (const float*)d_in[11];
  const float* bf  = (const float*)d_in[12];
  const float* bo  = (const float*)d_in[13];
  const float* bp  = (const float*)d_in[14];
  float* out = (float*)d_out;

  // ws layout: [0,1MB) hT fp16 double buffer [2][B][H];
  //            [1MB, 1MB+16KB) per-producer flags (256 x 64B)
  _Float16* hT = (_Float16*)d_ws;
  const size_t hT_bytes = (size_t)2 * B_ * H_ * sizeof(_Float16);  // 1 MiB
  unsigned int* flags = (unsigned int*)((char*)d_ws + hT_bytes);

  hipMemsetAsync(d_ws, 0, hT_bytes + 16384, stream);  // h(0)=0, flags=0

  lstm_main<<<256, 512, 0, stream>>>(x, Wgh, Wih, Wfh, Woh,
                                     Wgx, Wix, Wfx, Wox,
                                     bg, bi, bf, bo, hT, flags);
  lstm_proj<<<256, 64, 0, stream>>>(hT, Wph, bp, out);
}